// Round 2
// baseline (212.538 us; speedup 1.0000x reference)
//
#include <hip/hip_runtime.h>
#include <cstdint>

#define B_SZ 64
#define N_SZ 640
#define H_SZ 768
#define LN_EPS 1e-5f

// ---------------- K1: e0[b,:] = row-0 embedding after node aggregation ----------------
__global__ void k_embed0(const int* __restrict__ inputs,
                         const int* __restrict__ pos,
                         const int* __restrict__ amask,      // [B,N,N] bool promoted to int32
                         const float* __restrict__ emb,      // [V,H]
                         float* __restrict__ e0) {           // [B,H]
    const int b   = blockIdx.x;
    const int tid = threadIdx.x;

    const int pos0 = pos[b * N_SZ];
    if (pos0 != 0) {
        // not a DFG node: plain word embedding of token 0
        const size_t row = (size_t)inputs[b * N_SZ] * H_SZ;
        for (int h = tid; h < H_SZ; h += 256)
            e0[b * H_SZ + h] = emb[row + h];
        return;
    }

    // active = token_mask (pos>=2) && attn_mask[b,0,m]; deterministic order scan
    __shared__ uint8_t act[N_SZ];
    const size_t mbase = (size_t)b * N_SZ * N_SZ;  // row 0 of attn_mask
    for (int m = tid; m < N_SZ; m += 256)
        act[m] = (pos[b * N_SZ + m] >= 2 && amask[mbase + m] != 0) ? 1 : 0;
    __syncthreads();

    float a0 = 0.f, a1 = 0.f, a2 = 0.f;
    int cnt = 0;
    for (int m = 0; m < N_SZ; ++m) {
        if (act[m]) {
            ++cnt;
            const size_t row = (size_t)inputs[b * N_SZ + m] * H_SZ;
            a0 += emb[row + tid];
            a1 += emb[row + tid + 256];
            a2 += emb[row + tid + 512];
        }
    }
    const float scale = 1.0f / ((float)cnt + 1e-10f);
    e0[b * H_SZ + tid]       = a0 * scale;
    e0[b * H_SZ + tid + 256] = a1 * scale;
    e0[b * H_SZ + tid + 512] = a2 * scale;
}

// ---------------- K2/K3: y[b,j] = act( sum_k x[b,k] * w[k,j] + bias[j] ) ----------------
template <int ACT>  // 0 = tanh, 1 = exact gelu
__global__ void k_gemv(const float* __restrict__ x,    // [B,H]
                       const float* __restrict__ w,    // [H,H] row-major (k,j)
                       const float* __restrict__ bias, // [H]
                       float* __restrict__ y) {        // [B,H]
    const int b = blockIdx.y;
    const int j = blockIdx.x * 256 + threadIdx.x;
    __shared__ float xs[H_SZ];
    for (int h = threadIdx.x; h < H_SZ; h += 256)
        xs[h] = x[b * H_SZ + h];
    __syncthreads();

    float acc = 0.f;
#pragma unroll 8
    for (int k = 0; k < H_SZ; ++k)
        acc = fmaf(xs[k], w[k * H_SZ + j], acc);
    acc += bias[j];
    if (ACT == 0) {
        acc = tanhf(acc);
    } else {
        acc = acc * 0.5f * (1.0f + erff(acc * 0.70710678118654752f));
    }
    y[b * H_SZ + j] = acc;
}

// ---------------- K4: LayerNorm + decoder dot + tanh ----------------
__global__ void k_final(const float* __restrict__ x,   // [B,H]
                        const float* __restrict__ g,
                        const float* __restrict__ beta,
                        const float* __restrict__ dw,  // [H]
                        const float* __restrict__ db,  // [1]
                        float* __restrict__ out) {     // [B]
    const int b    = blockIdx.x;
    const int tid  = threadIdx.x;
    const int lane = tid & 63;
    const int wave = tid >> 6;
    __shared__ float red[8];

    const float v0 = x[b * H_SZ + tid];
    const float v1 = x[b * H_SZ + tid + 256];
    const float v2 = x[b * H_SZ + tid + 512];

    // pass 1: mean
    float s = v0 + v1 + v2;
    for (int o = 32; o > 0; o >>= 1) s += __shfl_down(s, o, 64);
    if (lane == 0) red[wave] = s;
    __syncthreads();
    if (tid == 0) red[0] = red[0] + red[1] + red[2] + red[3];
    __syncthreads();
    const float mean = red[0] * (1.0f / H_SZ);
    __syncthreads();

    // pass 2: variance of (x - mean)
    const float d0 = v0 - mean, d1 = v1 - mean, d2 = v2 - mean;
    float q = d0 * d0 + d1 * d1 + d2 * d2;
    for (int o = 32; o > 0; o >>= 1) q += __shfl_down(q, o, 64);
    if (lane == 0) red[wave] = q;
    __syncthreads();
    if (tid == 0) red[0] = red[0] + red[1] + red[2] + red[3];
    __syncthreads();
    const float rstd = rsqrtf(red[0] * (1.0f / H_SZ) + LN_EPS);
    __syncthreads();

    // normalize, scale/shift, dot with dec_w
    float p = 0.f;
    p += (d0 * rstd * g[tid]       + beta[tid])       * dw[tid];
    p += (d1 * rstd * g[tid + 256] + beta[tid + 256]) * dw[tid + 256];
    p += (d2 * rstd * g[tid + 512] + beta[tid + 512]) * dw[tid + 512];
    for (int o = 32; o > 0; o >>= 1) p += __shfl_down(p, o, 64);
    if (lane == 0) red[wave] = p;
    __syncthreads();
    if (tid == 0)
        out[b] = tanhf(red[0] + red[1] + red[2] + red[3] + db[0]);
}

extern "C" void kernel_launch(void* const* d_in, const int* in_sizes, int n_in,
                              void* d_out, int out_size, void* d_ws, size_t ws_size,
                              hipStream_t stream) {
    const int*   inputs = (const int*)d_in[0];
    const int*   pos    = (const int*)d_in[1];
    const int*   amask  = (const int*)d_in[2];
    const float* emb    = (const float*)d_in[3];
    const float* pw     = (const float*)d_in[4];
    const float* pb     = (const float*)d_in[5];
    const float* dw     = (const float*)d_in[6];
    const float* db     = (const float*)d_in[7];
    const float* lg     = (const float*)d_in[8];
    const float* lb     = (const float*)d_in[9];
    const float* decw   = (const float*)d_in[10];
    const float* decb   = (const float*)d_in[11];
    float* out = (float*)d_out;

    float* e0     = (float*)d_ws;               // [64,768]
    float* pooled = e0 + B_SZ * H_SZ;           // [64,768]
    float* xb     = pooled + B_SZ * H_SZ;       // [64,768]

    k_embed0<<<B_SZ, 256, 0, stream>>>(inputs, pos, amask, emb, e0);
    k_gemv<0><<<dim3(3, B_SZ), 256, 0, stream>>>(e0, pw, pb, pooled);
    k_gemv<1><<<dim3(3, B_SZ), 256, 0, stream>>>(pooled, dw, db, xb);
    k_final<<<B_SZ, 256, 0, stream>>>(xb, lg, lb, decw, decb, out);
}

// Round 4
// 94.225 us; speedup vs baseline: 2.2556x; 2.2556x over previous
//
#include <hip/hip_runtime.h>
#include <cstdint>

#define B_SZ 64
#define N_SZ 640
#define H_SZ 768
#define NCHUNK 32
#define CHUNK (N_SZ / NCHUNK)   // 20
#define LN_EPS 1e-5f

// ---------------- K1a: partial masked sums over a 20-token chunk ----------------
__global__ void k_embed_partial(const int* __restrict__ inputs,
                                const int* __restrict__ pos,
                                const int* __restrict__ amask,   // [B,N,N] bool->int32
                                const float* __restrict__ emb,   // [V,H]
                                float* __restrict__ partials,    // [B,NCHUNK,H]
                                float* __restrict__ counts) {    // [B,NCHUNK]
    const int c   = blockIdx.x;
    const int b   = blockIdx.y;
    const int tid = threadIdx.x;

    if (pos[b * N_SZ] != 0) return;  // non-node batch: reduce kernel handles it

    __shared__ float wgt[CHUNK];
    __shared__ int   rowid[CHUNK];
    if (tid < CHUNK) {
        const int m = c * CHUNK + tid;
        const int active = (pos[b * N_SZ + m] >= 2) &&
                           (amask[(size_t)b * N_SZ * N_SZ + m] != 0);
        wgt[tid]   = active ? 1.0f : 0.0f;
        rowid[tid] = inputs[b * N_SZ + m];
    }
    __syncthreads();

    // predicated, branch-free accumulate: all loads independent -> deep pipelining
    float a0 = 0.f, a1 = 0.f, a2 = 0.f;
#pragma unroll 5
    for (int m = 0; m < CHUNK; ++m) {
        const float  w   = wgt[m];
        const size_t row = (size_t)rowid[m] * H_SZ;
        a0 = fmaf(w, emb[row + tid],       a0);
        a1 = fmaf(w, emb[row + tid + 256], a1);
        a2 = fmaf(w, emb[row + tid + 512], a2);
    }
    float* pout = partials + ((size_t)b * NCHUNK + c) * H_SZ;
    pout[tid]       = a0;
    pout[tid + 256] = a1;
    pout[tid + 512] = a2;
    if (tid == 0) {
        float s = 0.f;
        for (int m = 0; m < CHUNK; ++m) s += wgt[m];
        counts[b * NCHUNK + c] = s;
    }
}

// ---------------- K1b: deterministic reduce of partials (or plain copy) ----------------
__global__ void k_embed_reduce(const int* __restrict__ inputs,
                               const int* __restrict__ pos,
                               const float* __restrict__ emb,
                               const float* __restrict__ partials,
                               const float* __restrict__ counts,
                               float* __restrict__ e0) {         // [B,H]
    const int b   = blockIdx.x;
    const int tid = threadIdx.x;

    if (pos[b * N_SZ] != 0) {
        const size_t row = (size_t)inputs[b * N_SZ] * H_SZ;
        for (int h = tid; h < H_SZ; h += 256)
            e0[b * H_SZ + h] = emb[row + h];
        return;
    }

    float cnt = 0.f;
    for (int c = 0; c < NCHUNK; ++c) cnt += counts[b * NCHUNK + c];
    const float scale = 1.0f / (cnt + 1e-10f);

    float a0 = 0.f, a1 = 0.f, a2 = 0.f;
    const float* p = partials + (size_t)b * NCHUNK * H_SZ;
#pragma unroll 8
    for (int c = 0; c < NCHUNK; ++c) {
        a0 += p[c * H_SZ + tid];
        a1 += p[c * H_SZ + tid + 256];
        a2 += p[c * H_SZ + tid + 512];
    }
    e0[b * H_SZ + tid]       = a0 * scale;
    e0[b * H_SZ + tid + 256] = a1 * scale;
    e0[b * H_SZ + tid + 512] = a2 * scale;
}

// ---------------- K2/K3: y[b,j] = act( sum_k x[b,k] * w[k,j] + bias[j] ) ----------------
template <int ACT>  // 0 = tanh, 1 = exact gelu
__global__ void k_gemv(const float* __restrict__ x,    // [B,H]
                       const float* __restrict__ w,    // [H,H] row-major (k,j)
                       const float* __restrict__ bias, // [H]
                       float* __restrict__ y) {        // [B,H]
    const int b = blockIdx.y;
    const int j = blockIdx.x * 256 + threadIdx.x;
    __shared__ float xs[H_SZ];
    for (int h = threadIdx.x; h < H_SZ; h += 256)
        xs[h] = x[b * H_SZ + h];
    __syncthreads();

    float acc = 0.f;
#pragma unroll 8
    for (int k = 0; k < H_SZ; ++k)
        acc = fmaf(xs[k], w[k * H_SZ + j], acc);
    acc += bias[j];
    if (ACT == 0) {
        acc = tanhf(acc);
    } else {
        acc = acc * 0.5f * (1.0f + erff(acc * 0.70710678118654752f));
    }
    y[b * H_SZ + j] = acc;
}

// ---------------- K4: LayerNorm + decoder dot + tanh ----------------
__global__ void k_final(const float* __restrict__ x,   // [B,H]
                        const float* __restrict__ g,
                        const float* __restrict__ beta,
                        const float* __restrict__ dw,  // [H]
                        const float* __restrict__ db,  // [1]
                        float* __restrict__ out) {     // [B]
    const int b    = blockIdx.x;
    const int tid  = threadIdx.x;
    const int lane = tid & 63;
    const int wave = tid >> 6;
    __shared__ float red[8];

    const float v0 = x[b * H_SZ + tid];
    const float v1 = x[b * H_SZ + tid + 256];
    const float v2 = x[b * H_SZ + tid + 512];

    float s = v0 + v1 + v2;
    for (int o = 32; o > 0; o >>= 1) s += __shfl_down(s, o, 64);
    if (lane == 0) red[wave] = s;
    __syncthreads();
    if (tid == 0) red[0] = red[0] + red[1] + red[2] + red[3];
    __syncthreads();
    const float mean = red[0] * (1.0f / H_SZ);
    __syncthreads();

    const float d0 = v0 - mean, d1 = v1 - mean, d2 = v2 - mean;
    float q = d0 * d0 + d1 * d1 + d2 * d2;
    for (int o = 32; o > 0; o >>= 1) q += __shfl_down(q, o, 64);
    if (lane == 0) red[wave] = q;
    __syncthreads();
    if (tid == 0) red[0] = red[0] + red[1] + red[2] + red[3];
    __syncthreads();
    const float rstd = rsqrtf(red[0] * (1.0f / H_SZ) + LN_EPS);
    __syncthreads();

    float p = 0.f;
    p += (d0 * rstd * g[tid]       + beta[tid])       * dw[tid];
    p += (d1 * rstd * g[tid + 256] + beta[tid + 256]) * dw[tid + 256];
    p += (d2 * rstd * g[tid + 512] + beta[tid + 512]) * dw[tid + 512];
    for (int o = 32; o > 0; o >>= 1) p += __shfl_down(p, o, 64);
    if (lane == 0) red[wave] = p;
    __syncthreads();
    if (tid == 0)
        out[b] = tanhf(red[0] + red[1] + red[2] + red[3] + db[0]);
}

extern "C" void kernel_launch(void* const* d_in, const int* in_sizes, int n_in,
                              void* d_out, int out_size, void* d_ws, size_t ws_size,
                              hipStream_t stream) {
    const int*   inputs = (const int*)d_in[0];
    const int*   pos    = (const int*)d_in[1];
    const int*   amask  = (const int*)d_in[2];
    const float* emb    = (const float*)d_in[3];
    const float* pw     = (const float*)d_in[4];
    const float* pb     = (const float*)d_in[5];
    const float* dw     = (const float*)d_in[6];
    const float* db     = (const float*)d_in[7];
    const float* lg     = (const float*)d_in[8];
    const float* lb     = (const float*)d_in[9];
    const float* decw   = (const float*)d_in[10];
    const float* decb   = (const float*)d_in[11];
    float* out = (float*)d_out;

    float* partials = (float*)d_ws;                         // [64,32,768] = 6 MB
    float* counts   = partials + (size_t)B_SZ * NCHUNK * H_SZ; // [64,32]
    float* e0       = counts + B_SZ * NCHUNK;               // [64,768]
    float* pooled   = e0 + B_SZ * H_SZ;                     // [64,768]
    float* xb       = pooled + B_SZ * H_SZ;                 // [64,768]

    k_embed_partial<<<dim3(NCHUNK, B_SZ), 256, 0, stream>>>(inputs, pos, amask, emb,
                                                            partials, counts);
    k_embed_reduce<<<B_SZ, 256, 0, stream>>>(inputs, pos, emb, partials, counts, e0);
    k_gemv<0><<<dim3(3, B_SZ), 256, 0, stream>>>(e0, pw, pb, pooled);
    k_gemv<1><<<dim3(3, B_SZ), 256, 0, stream>>>(pooled, dw, db, xb);
    k_final<<<B_SZ, 256, 0, stream>>>(xb, lg, lb, decw, decb, out);
}

// Round 7
// 91.892 us; speedup vs baseline: 2.3129x; 1.0254x over previous
//
#include <hip/hip_runtime.h>
#include <cstdint>

#define B_SZ 64
#define N_SZ 640
#define H_SZ 768
#define NCHUNK 32
#define CHUNK (N_SZ / NCHUNK)   // 20
#define LN_EPS 1e-5f

// ---------------- K1: partial masked sums over a 20-token chunk ----------------
__global__ void k_embed_partial(const int* __restrict__ inputs,
                                const int* __restrict__ pos,
                                const int* __restrict__ amask,   // [B,N,N] bool->int32
                                const float* __restrict__ emb,   // [V,H]
                                float* __restrict__ partials,    // [B,NCHUNK,H]
                                float* __restrict__ counts) {    // [B,NCHUNK]
    const int c   = blockIdx.x;
    const int b   = blockIdx.y;
    const int tid = threadIdx.x;

    if (pos[b * N_SZ] != 0) return;  // non-node batch handled downstream

    __shared__ float wgt[CHUNK];
    __shared__ int   rowid[CHUNK];
    if (tid < CHUNK) {
        const int m = c * CHUNK + tid;
        const int active = (pos[b * N_SZ + m] >= 2) &&
                           (amask[(size_t)b * N_SZ * N_SZ + m] != 0);
        wgt[tid]   = active ? 1.0f : 0.0f;
        rowid[tid] = inputs[b * N_SZ + m];
    }
    __syncthreads();

    float a0 = 0.f, a1 = 0.f, a2 = 0.f;
#pragma unroll 10
    for (int m = 0; m < CHUNK; ++m) {
        const float  w   = wgt[m];
        const size_t row = (size_t)rowid[m] * H_SZ;
        a0 = fmaf(w, emb[row + tid],       a0);
        a1 = fmaf(w, emb[row + tid + 256], a1);
        a2 = fmaf(w, emb[row + tid + 512], a2);
    }
    float* pout = partials + ((size_t)b * NCHUNK + c) * H_SZ;
    pout[tid]       = a0;
    pout[tid + 256] = a1;
    pout[tid + 512] = a2;
    if (tid == 0) {
        float s = 0.f;
        for (int m = 0; m < CHUNK; ++m) s += wgt[m];
        counts[b * NCHUNK + c] = s;
    }
}

// ---------------- block-wide float2 sum over 768 threads (12 waves) ----------------
__device__ __forceinline__ float2 block_sum2(float2 v, float2* red2, int tid) {
    const int lane = tid & 63;
    const int wave = tid >> 6;
    for (int o = 32; o > 0; o >>= 1) {
        v.x += __shfl_down(v.x, o, 64);
        v.y += __shfl_down(v.y, o, 64);
    }
    if (lane == 0) red2[wave] = v;
    __syncthreads();
    if (tid == 0) {
        float2 s = make_float2(0.f, 0.f);
        for (int i = 0; i < 12; ++i) { s.x += red2[i].x; s.y += red2[i].y; }
        red2[0] = s;
    }
    __syncthreads();
    const float2 s = red2[0];
    __syncthreads();  // red2 reusable after return
    return s;
}

// ---------------- K2: e0 (reduce partials / copy row) + pooler gemv + tanh, 2 batches ----------------
__global__ __launch_bounds__(768) void k_pooler(const int* __restrict__ inputs,
                                                const int* __restrict__ pos,
                                                const float* __restrict__ emb,
                                                const float* __restrict__ partials,
                                                const float* __restrict__ counts,
                                                const float* __restrict__ pw,   // [H,H]
                                                const float* __restrict__ pb,
                                                float* __restrict__ pooled) {   // [B,H]
    const int b0 = blockIdx.x * 2;
    const int j  = threadIdx.x;            // 0..767, one output column each
    __shared__ float2 xs[H_SZ];            // e0 for the two batches, interleaved

    float v[2];
#pragma unroll
    for (int p = 0; p < 2; ++p) {
        const int b = b0 + p;
        if (pos[b * N_SZ] != 0) {
            v[p] = emb[(size_t)inputs[b * N_SZ] * H_SZ + j];
        } else {
            float cnt = 0.f;
            for (int c = 0; c < NCHUNK; ++c) cnt += counts[b * NCHUNK + c];
            const float scale = 1.0f / (cnt + 1e-10f);
            float a = 0.f;
            const float* pp = partials + (size_t)b * NCHUNK * H_SZ + j;
#pragma unroll 8
            for (int c = 0; c < NCHUNK; ++c) a += pp[(size_t)c * H_SZ];
            v[p] = a * scale;
        }
    }
    xs[j] = make_float2(v[0], v[1]);
    __syncthreads();

    float acc0 = 0.f, acc1 = 0.f;
#pragma unroll 8
    for (int k = 0; k < H_SZ; ++k) {
        const float  wv = pw[k * H_SZ + j];
        const float2 xv = xs[k];
        acc0 = fmaf(wv, xv.x, acc0);
        acc1 = fmaf(wv, xv.y, acc1);
    }
    const float bj = pb[j];
    pooled[(size_t)b0 * H_SZ + j]       = tanhf(acc0 + bj);
    pooled[(size_t)(b0 + 1) * H_SZ + j] = tanhf(acc1 + bj);
}

// ---------------- K3: gelu gemv + LayerNorm + decoder dot + tanh, 2 batches ----------------
__global__ __launch_bounds__(768) void k_lmhead(const float* __restrict__ pooled,
                                                const float* __restrict__ dwm,  // dense_w [H,H]
                                                const float* __restrict__ dbv,  // dense_b [H]
                                                const float* __restrict__ lg,
                                                const float* __restrict__ lb,
                                                const float* __restrict__ decw, // [H]
                                                const float* __restrict__ decb, // [1]
                                                float* __restrict__ out) {      // [B]
    const int b0 = blockIdx.x * 2;
    const int j  = threadIdx.x;
    __shared__ float2 xs[H_SZ];
    __shared__ float2 red2[12];

    xs[j] = make_float2(pooled[(size_t)b0 * H_SZ + j],
                        pooled[(size_t)(b0 + 1) * H_SZ + j]);
    __syncthreads();

    float acc0 = 0.f, acc1 = 0.f;
#pragma unroll 8
    for (int k = 0; k < H_SZ; ++k) {
        const float  wv = dwm[k * H_SZ + j];
        const float2 xv = xs[k];
        acc0 = fmaf(wv, xv.x, acc0);
        acc1 = fmaf(wv, xv.y, acc1);
    }
    const float bj = dbv[j];
    acc0 += bj; acc1 += bj;
    // exact gelu
    const float g0 = acc0 * 0.5f * (1.0f + erff(acc0 * 0.70710678118654752f));
    const float g1 = acc1 * 0.5f * (1.0f + erff(acc1 * 0.70710678118654752f));
    __syncthreads();  // done reading xs

    // LayerNorm over H for both batches
    const float2 sum = block_sum2(make_float2(g0, g1), red2, j);
    const float mean0 = sum.x * (1.0f / H_SZ);
    const float mean1 = sum.y * (1.0f / H_SZ);
    const float d0 = g0 - mean0, d1 = g1 - mean1;
    const float2 qs = block_sum2(make_float2(d0 * d0, d1 * d1), red2, j);
    const float rstd0 = rsqrtf(qs.x * (1.0f / H_SZ) + LN_EPS);
    const float rstd1 = rsqrtf(qs.y * (1.0f / H_SZ) + LN_EPS);

    const float gj = lg[j], betaj = lb[j], dj = decw[j];
    const float p0 = (d0 * rstd0 * gj + betaj) * dj;
    const float p1 = (d1 * rstd1 * gj + betaj) * dj;
    const float2 dot = block_sum2(make_float2(p0, p1), red2, j);
    if (j == 0) {
        const float dbias = decb[0];
        out[b0]     = tanhf(dot.x + dbias);
        out[b0 + 1] = tanhf(dot.y + dbias);
    }
}

extern "C" void kernel_launch(void* const* d_in, const int* in_sizes, int n_in,
                              void* d_out, int out_size, void* d_ws, size_t ws_size,
                              hipStream_t stream) {
    const int*   inputs = (const int*)d_in[0];
    const int*   pos    = (const int*)d_in[1];
    const int*   amask  = (const int*)d_in[2];
    const float* emb    = (const float*)d_in[3];
    const float* pw     = (const float*)d_in[4];
    const float* pb     = (const float*)d_in[5];
    const float* dw     = (const float*)d_in[6];
    const float* db     = (const float*)d_in[7];
    const float* lg     = (const float*)d_in[8];
    const float* lb     = (const float*)d_in[9];
    const float* decw   = (const float*)d_in[10];
    const float* decb   = (const float*)d_in[11];
    float* out = (float*)d_out;

    float* partials = (float*)d_ws;                            // [64,32,768]
    float* counts   = partials + (size_t)B_SZ * NCHUNK * H_SZ; // [64,32]
    float* pooled   = counts + B_SZ * NCHUNK;                  // [64,768]

    k_embed_partial<<<dim3(NCHUNK, B_SZ), 256, 0, stream>>>(inputs, pos, amask, emb,
                                                            partials, counts);
    k_pooler<<<B_SZ / 2, 768, 0, stream>>>(inputs, pos, emb, partials, counts,
                                           pw, pb, pooled);
    k_lmhead<<<B_SZ / 2, 768, 0, stream>>>(pooled, dw, db, lg, lb, decw, decb, out);
}